// Round 18
// baseline (298.603 us; speedup 1.0000x reference)
//
#include <hip/hip_runtime.h>
#include <hip/hip_bf16.h>

// B=4, S=2048, D=1024, H=16, DH=64. MHA forward, causal, f32 io.
// fused QKV proj GEMM reads f32 q/k/v directly: A fragments loaded straight
// from global into registers (one K-step prefetch, two named sets), cvt_pk on
// use; B (bf16 weights) via global_load_lds double-buffer. Q pre-scaled
// 0.125*log2e; V written transposed. -> flash attn (32x32 MFMA, swapped QK^T,
// in-register P) -> out GEMM (R13 bf16 path). Weights cvt'd once.

#define B_ 4
#define S_ 2048
#define D_ 1024
#define H_ 16
#define DH_ 64
#define M_ (B_*S_)
#define MASKADD (-14427.0f)    // -10000 * log2(e)
#define QSCALE  (0.180336880f) // 0.125 * log2(e)

typedef __attribute__((ext_vector_type(8)))  __bf16 bf16x8;
typedef __attribute__((ext_vector_type(8)))  unsigned short ushort8;
typedef __attribute__((ext_vector_type(4)))  float f32x4;
typedef __attribute__((ext_vector_type(16))) float f32x16;

__device__ __forceinline__ unsigned short f2bf(float f) {
  __hip_bfloat16 h = __float2bfloat16(f);
  union { __hip_bfloat16 h; unsigned short u; } c; c.h = h; return c.u;
}

__device__ __forceinline__ f32x4 mfma16(bf16x8 a, bf16x8 b, f32x4 c) {
  return __builtin_amdgcn_mfma_f32_16x16x32_bf16(a, b, c, 0, 0, 0);
}
__device__ __forceinline__ f32x16 mfma32(bf16x8 a, bf16x8 b, f32x16 c) {
  return __builtin_amdgcn_mfma_f32_32x32x16_bf16(a, b, c, 0, 0, 0);
}

__device__ __forceinline__ unsigned cvtpk(float lo, float hi) {
  unsigned r;
  asm("v_cvt_pk_bf16_f32 %0, %1, %2" : "=v"(r) : "v"(lo), "v"(hi));
  return r;
}

__device__ __forceinline__ void gld_lds16(const void* g, void* l) {
  __builtin_amdgcn_global_load_lds(
      (const __attribute__((address_space(1))) unsigned int*)g,
      (__attribute__((address_space(3))) unsigned int*)l, 16, 0, 0);
}

// ---------------- f32 -> bf16 conversion (weights only) ----------------
__global__ void cvt4_kernel(const float* __restrict__ p0, const float* __restrict__ p1,
                            const float* __restrict__ p2, const float* __restrict__ p3,
                            unsigned short* __restrict__ o0, unsigned short* __restrict__ o1,
                            unsigned short* __restrict__ o2, unsigned short* __restrict__ o3,
                            int n4) {
  int i = blockIdx.x * blockDim.x + threadIdx.x;
  if (i >= n4) return;
  const float* in  = (blockIdx.y == 0) ? p0 : (blockIdx.y == 1 ? p1 : (blockIdx.y == 2 ? p2 : p3));
  unsigned short* out = (blockIdx.y == 0) ? o0 : (blockIdx.y == 1 ? o1 : (blockIdx.y == 2 ? o2 : o3));
  float4 f = reinterpret_cast<const float4*>(in)[i];
  ushort4 o;
  o.x = f2bf(f.x); o.y = f2bf(f.y); o.z = f2bf(f.z); o.w = f2bf(f.w);
  reinterpret_cast<ushort4*>(out)[i] = o;
}

// ---------------- epilogue (shared) ----------------
__device__ __forceinline__
void gemm_epilogue(f32x4 (&acc)[4][4], const float* __restrict__ bias,
                   void* __restrict__ outp, int mode, bool sc,
                   int m0, int n0, int wr, int wc, int lane)
{
  #pragma unroll
  for (int i = 0; i < 4; ++i) {
    int gr0 = m0 + 64*wr + 16*i + ((lane >> 4) << 2);
    #pragma unroll
    for (int j = 0; j < 4; ++j) {
      int gc = n0 + 64*wc + 16*j + (lane & 15);
      float bv = bias[gc];
      if (mode == 2) {
        int b = gr0 >> 11, s = gr0 & (S_ - 1);
        int hh = gc >> 6, dh = gc & (DH_ - 1);
        ushort4 o;
        o.x = f2bf(acc[i][j][0] + bv); o.y = f2bf(acc[i][j][1] + bv);
        o.z = f2bf(acc[i][j][2] + bv); o.w = f2bf(acc[i][j][3] + bv);
        *(ushort4*)&((unsigned short*)outp)[(((size_t)b*H_ + hh)*DH_ + dh)*S_ + s] = o;
      } else {
        #pragma unroll
        for (int r = 0; r < 4; ++r) {
          float v = acc[i][j][r] + bv;
          if (sc) v *= QSCALE;
          int gr = gr0 + r;
          if (mode == 0) {
            int b = gr >> 11, s = gr & (S_ - 1);
            int hh = gc >> 6, dh = gc & (DH_ - 1);
            ((unsigned short*)outp)[(((size_t)b*H_ + hh)*S_ + s)*DH_ + dh] = f2bf(v);
          } else {
            ((float*)outp)[(size_t)gr*D_ + gc] = v;
          }
        }
      }
    }
  }
}

// ---------------- QKV GEMM: f32 A in registers, B via LDS ------------------
// Tile 128x128, BK=32, 4 waves. A fragments (8 f32 per frag x 4 frags) loaded
// from global one K-step ahead into alternating named register sets; cvt_pk
// on use. B double-buffered via global_load_lds, 1 barrier per K-step.
__global__ __launch_bounds__(256)
void gemm_qkv(const float* __restrict__ Aq, const float* __restrict__ Ak,
              const float* __restrict__ Av,
              const unsigned short* __restrict__ Wq_, const unsigned short* __restrict__ Wk_,
              const unsigned short* __restrict__ Wv_,
              const float* __restrict__ bq_, const float* __restrict__ bk_,
              const float* __restrict__ bv_,
              unsigned short* __restrict__ Oq, unsigned short* __restrict__ Ok,
              unsigned short* __restrict__ Ov)
{
  __shared__ unsigned short sB[2*4096];     // 16 KB
  const int y = blockIdx.y;
  const float* A = (y == 0) ? Aq : (y == 1 ? Ak : Av);
  const unsigned short* W = (y == 0) ? Wq_ : (y == 1 ? Wk_ : Wv_);
  const float* bias        = (y == 0) ? bq_ : (y == 1 ? bk_ : bv_);
  unsigned short* outp     = (y == 0) ? Oq  : (y == 1 ? Ok  : Ov);
  const int mode = (y == 2) ? 2 : 0;
  const bool sc = (y == 0);

  const int tid  = threadIdx.x;
  const int lane = tid & 63, wid = tid >> 6;
  const int bx = blockIdx.x;
  const int j8 = bx & 7, i8 = bx >> 3;
  const int mt = j8*8 + (i8 >> 3), nt = i8 & 7;   // bijective: 64 x 8
  const int m0 = mt*128, n0 = nt*128;
  const int wr = wid >> 1, wc = wid & 1;
  const int g = lane >> 4;

  f32x4 acc[4][4];
  #pragma unroll
  for (int i = 0; i < 4; ++i)
    #pragma unroll
    for (int j = 0; j < 4; ++j)
      #pragma unroll
      for (int r = 0; r < 4; ++r) acc[i][j][r] = 0.0f;

  auto stageB = [&](int bufi, int kt) {
    const unsigned short* Wb = W + (size_t)n0*D_ + kt*32;
    #pragma unroll
    for (int p = 0; p < 2; ++p) {
      int r = 32*wid + 16*p + (lane >> 2);
      int c = (lane & 3) * 8;
      gld_lds16(Wb + (size_t)r*D_ + c, &sB[bufi*4096 + (32*wid + 16*p)*32]);
    }
  };

  // per-lane A row base pointers (frag i: row m0+64wr+16i+(lane&15))
  const float* arow[4];
  #pragma unroll
  for (int i = 0; i < 4; ++i)
    arow[i] = A + (size_t)(m0 + 64*wr + 16*i + (lane & 15))*D_ + g*8;

  f32x4 aR0[4][2], aR1[4][2];
  auto loadA = [&](int kt, f32x4 (*aR)[2]) {
    #pragma unroll
    for (int i = 0; i < 4; ++i) {
      const float* p = arow[i] + kt*32;
      aR[i][0] = *(const f32x4*)(p);
      aR[i][1] = *(const f32x4*)(p + 4);
    }
  };
  auto mfmaStep = [&](const f32x4 (*aR)[2], int bufi) {
    bf16x8 aF[4], bF[4];
    #pragma unroll
    for (int i = 0; i < 4; ++i) {
      union { unsigned u[4]; bf16x8 v; } af;
      af.u[0] = cvtpk(aR[i][0][0], aR[i][0][1]);
      af.u[1] = cvtpk(aR[i][0][2], aR[i][0][3]);
      af.u[2] = cvtpk(aR[i][1][0], aR[i][1][1]);
      af.u[3] = cvtpk(aR[i][1][2], aR[i][1][3]);
      aF[i] = af.v;
    }
    #pragma unroll
    for (int j = 0; j < 4; ++j)
      bF[j] = *(const bf16x8*)&sB[bufi*4096 + (64*wc + 16*j + (lane & 15))*32 + g*8];
    #pragma unroll
    for (int i = 0; i < 4; ++i)
      #pragma unroll
      for (int j = 0; j < 4; ++j)
        acc[i][j] = mfma16(aF[i], bF[j], acc[i][j]);
  };

  // prologue
  loadA(0, aR0);
  stageB(0, 0);

  const int NK = D_/32;                      // 32 (even)
  for (int it = 0; it < NK/2; ++it) {
    const int kt0 = 2*it;

    __syncthreads();                         // B tile kt0 ready (buf0)
    stageB(1, kt0 + 1);
    loadA(kt0 + 1, aR1);                     // register prefetch
    mfmaStep(aR0, 0);

    __syncthreads();                         // B tile kt0+1 ready (buf1)
    if (kt0 + 2 < NK) {
      stageB(0, kt0 + 2);
      loadA(kt0 + 2, aR0);
    }
    mfmaStep(aR1, 1);
  }

  gemm_epilogue(acc, bias, outp, mode, sc, m0, n0, wr, wc, lane);
}

// ---------------- out GEMM: bf16 A + B via LDS (R13 path) ------------------
__global__ __launch_bounds__(256, 3)
void gemm_out(const unsigned short* __restrict__ A, const unsigned short* __restrict__ W,
              const float* __restrict__ bias, float* __restrict__ outp)
{
  __shared__ unsigned short sA[2*4096];   // 16 KB
  __shared__ unsigned short sB[2*4096];   // 16 KB

  const int tid  = threadIdx.x;
  const int lane = tid & 63, wid = tid >> 6;
  const int bx = blockIdx.x;
  const int j8 = bx & 7, i8 = bx >> 3;
  const int mt = j8*8 + (i8 >> 3), nt = i8 & 7;
  const int m0 = mt*128, n0 = nt*128;
  const int wr = wid >> 1, wc = wid & 1;
  const int g = lane >> 4;

  f32x4 acc[4][4];
  #pragma unroll
  for (int i = 0; i < 4; ++i)
    #pragma unroll
    for (int j = 0; j < 4; ++j)
      #pragma unroll
      for (int r = 0; r < 4; ++r) acc[i][j][r] = 0.0f;

  auto stage = [&](int bufi, int kt) {
    const unsigned short* Ab = A + (size_t)m0*D_ + kt*32;
    const unsigned short* Wb = W + (size_t)n0*D_ + kt*32;
    #pragma unroll
    for (int p = 0; p < 2; ++p) {
      int r = 32*wid + 16*p + (lane >> 2);
      int c = (lane & 3) * 8;
      gld_lds16(Ab + (size_t)r*D_ + c, &sA[bufi*4096 + (32*wid + 16*p)*32]);
      gld_lds16(Wb + (size_t)r*D_ + c, &sB[bufi*4096 + (32*wid + 16*p)*32]);
    }
  };

  stage(0, 0);
  const int NK = D_/32;
  int buf = 0;
  for (int kt = 0; kt < NK; ++kt) {
    __syncthreads();
    if (kt + 1 < NK) stage(buf ^ 1, kt + 1);
    bf16x8 aF[4], bF[4];
    #pragma unroll
    for (int i = 0; i < 4; ++i)
      aF[i] = *(const bf16x8*)&sA[buf*4096 + (64*wr + 16*i + (lane & 15))*32 + g*8];
    #pragma unroll
    for (int j = 0; j < 4; ++j)
      bF[j] = *(const bf16x8*)&sB[buf*4096 + (64*wc + 16*j + (lane & 15))*32 + g*8];
    #pragma unroll
    for (int i = 0; i < 4; ++i)
      #pragma unroll
      for (int j = 0; j < 4; ++j)
        acc[i][j] = mfma16(aF[i], bF[j], acc[i][j]);
    buf ^= 1;
  }

  gemm_epilogue(acc, bias, outp, 1, false, m0, n0, wr, wc, lane);
}

// ---------------- Flash attention (32x32 MFMA, in-register P) --------------
// grid (64 bh, 16): bx = bh (XCD-local K/V), by -> chunk = 15-by (longest
// first). Block = 4 waves x 32 q-rows = 128 q. Wave w: q = chunk*128 + w*32
// + (lane&31). KVBLK=64 staged tile (two 32-kv subtiles), double-buffered,
// XOR-swizzled rows, 1 barrier/tile.
// QK^T swapped at 32x32: S^T lane layout q=lane&31, kv=(r&3)+8(r>>2)+4(l>>5).
// Operand k-layout (stacked K8 blocks): C-regs st[8hh+j] ARE the PV B-operand
// fragment for kv-chunk hh -- pack with 4 cvt_pk, no cross-lane ops.
// vf loads match: two b64 reads at X and X+16, X = 64*sub+32*hh+8*h5.
__global__ __launch_bounds__(256)
void attn_kernel(const unsigned short* __restrict__ Qh, const unsigned short* __restrict__ Kh,
                 const unsigned short* __restrict__ Vt, unsigned short* __restrict__ AO)
{
  __shared__ unsigned short sK [2][64*64];
  __shared__ unsigned short sVt[2][64*64];

  const int tid = threadIdx.x, lane = tid & 63, wid = tid >> 6;
  const int l31 = lane & 31, h5 = lane >> 5;
  const int bh = blockIdx.x;
  const int chunk = 15 - (int)blockIdx.y;
  const int bb = bh >> 4, hd = bh & 15;
  const unsigned short* Qb = Qh + (size_t)bh * S_ * DH_;
  const unsigned short* Kb = Kh + (size_t)bh * S_ * DH_;
  const unsigned short* Vb = Vt + (size_t)bh * DH_ * S_;
  const int qc0 = chunk * 128;
  const int NT  = 2*chunk + 2;
  const int qw0 = qc0 + wid*32;            // wave's first q row
  const int q   = qw0 + l31;               // this lane's q row

  bf16x8 qF[4];
  #pragma unroll
  for (int c = 0; c < 4; ++c)
    qF[c] = *(const bf16x8*)(Qb + (size_t)q*DH_ + c*16 + h5*8);

  f32x16 zz;
  #pragma unroll
  for (int r = 0; r < 16; ++r) zz[r] = 0.0f;
  f32x16 accO0 = zz, accO1 = zz;           // d-halves 0..31, 32..63
  float lsum = 0.0f;

  auto stageK = [&](int bufi, int t) {
    #pragma unroll
    for (int p = 0; p < 2; ++p) {
      int ch = 2*wid + p;
      int row = ch*8 + (lane >> 3);
      int cbs = ((lane & 7) * 16) ^ ((row & 7) << 4);
      gld_lds16(Kb + (size_t)(t*64 + row)*DH_ + (cbs >> 1), &sK[bufi][ch*512]);
    }
  };
  auto stageV = [&](int bufi, int t) {
    #pragma unroll
    for (int p = 0; p < 2; ++p) {
      int ch = 2*wid + p;
      int row = ch*8 + (lane >> 3);          // row = dh
      int cbs = ((lane & 7) * 16) ^ ((row & 7) << 4);
      gld_lds16(Vb + (size_t)row*S_ + t*64 + (cbs >> 1), &sVt[bufi][ch*512]);
    }
  };

  stageK(0, 0);
  stageV(0, 0);

  int buf = 0;
  for (int t = 0; t < NT; ++t) {
    __syncthreads();        // tile t staged; prev-buf reads complete
    if (t + 1 < NT) { stageK(buf ^ 1, t + 1); stageV(buf ^ 1, t + 1); }

    #pragma unroll
    for (int sub = 0; sub < 2; ++sub) {
      const int kv0 = t*64 + sub*32;
      if (kv0 > qw0 + 31) continue;          // subtile fully masked (uniform)
      const bool dodiag = (kv0 + 31 > qw0);

      // ---- QK^T: S^T = K Q^T, chained over 4 d-chunks ----
      f32x16 st = zz;
      __builtin_amdgcn_s_setprio(1);
      #pragma unroll
      for (int c = 0; c < 4; ++c) {
        int row = sub*32 + l31;              // kv row in tile
        const char* base = (const char*)&sK[buf][0] + row*128;
        bf16x8 kf = *(const bf16x8*)(base + ((32*c + 16*h5) ^ ((row & 7) << 4)));
        st = mfma32(kf, qF[c], st);
      }
      __builtin_amdgcn_s_setprio(0);

      // ---- mask + exp2 + row-sum ----
      #pragma unroll
      for (int r = 0; r < 16; ++r) {
        float x = st[r];
        if (dodiag) {
          int kv = kv0 + (r & 3) + 8*(r >> 2) + 4*h5;
          if (kv > q) x += MASKADD;
        }
        x = __builtin_amdgcn_exp2f(x);
        st[r] = x;
        lsum += x;
      }

      // ---- per 16-kv chunk: pack P (C-regs are the B fragment), PV ----
      #pragma unroll
      for (int hh = 0; hh < 2; ++hh) {
        union { unsigned u[4]; bf16x8 v; } pb;
        pb.u[0] = cvtpk(st[8*hh+0], st[8*hh+1]);
        pb.u[1] = cvtpk(st[8*hh+2], st[8*hh+3]);
        pb.u[2] = cvtpk(st[8*hh+4], st[8*hh+5]);
        pb.u[3] = cvtpk(st[8*hh+6], st[8*hh+7]);

        __builtin_amdgcn_s_setprio(1);
        #pragma unroll
        for (int dh = 0; dh < 2; ++dh) {
          int row = dh*32 + l31;             // d row
          const char* base = (const char*)&sVt[buf][0] + row*128;
          int sw = (row & 7) << 4;
          int X = 64*sub + 32*hh + 8*h5;
          union { uint2 g[2]; bf16x8 v; } vv;
          vv.g[0] = *(const uint2*)(base + ((X)      ^ sw));
          vv.g[1] = *(const uint2*)(base + ((X + 16) ^ sw));
          if (dh == 0) accO0 = mfma32(vv.v, pb.v, accO0);
          else         accO1 = mfma32(vv.v, pb.v, accO1);
        }
        __builtin_amdgcn_s_setprio(0);
      }
    }
    buf ^= 1;
  }

  // ---- epilogue: combine the two kv-half sums, scale, store ----
  float lt = lsum + __shfl_xor(lsum, 32, 64);
  float inv = 1.0f / lt;
  unsigned short* ao = AO + ((size_t)bb*S_ + q)*D_ + hd*DH_;
  #pragma unroll
  for (int dh = 0; dh < 2; ++dh) {
    const f32x16 A = dh ? accO1 : accO0;
    #pragma unroll
    for (int rq = 0; rq < 4; ++rq) {
      ushort4 o;
      o.x = f2bf(A[4*rq+0] * inv);
      o.y = f2bf(A[4*rq+1] * inv);
      o.z = f2bf(A[4*rq+2] * inv);
      o.w = f2bf(A[4*rq+3] * inv);
      int dbase = dh*32 + 8*rq + 4*h5;       // d = dbase + (r&3)
      *(ushort4*)&ao[dbase] = o;
    }
  }
}

// ---------------- launch ----------------
extern "C" void kernel_launch(void* const* d_in, const int* in_sizes, int n_in,
                              void* d_out, int out_size, void* d_ws, size_t ws_size,
                              hipStream_t stream)
{
  const float* q  = (const float*)d_in[0];
  const float* k  = (const float*)d_in[1];
  const float* v  = (const float*)d_in[2];
  const float* Wq = (const float*)d_in[4];
  const float* bq = (const float*)d_in[5];
  const float* Wk = (const float*)d_in[6];
  const float* bk = (const float*)d_in[7];
  const float* Wv = (const float*)d_in[8];
  const float* bv = (const float*)d_in[9];
  const float* Wo = (const float*)d_in[10];
  const float* bo = (const float*)d_in[11];

  unsigned short* ws = (unsigned short*)d_ws;
  const size_t MD = (size_t)M_ * D_;
  const size_t DD = (size_t)D_ * D_;
  unsigned short* Wqb = ws;
  unsigned short* Wkb = Wqb + DD;
  unsigned short* Wvb = Wkb + DD;
  unsigned short* Wob = Wvb + DD;
  unsigned short* Qhb = Wob + DD;
  unsigned short* Khb = Qhb + MD;
  unsigned short* Vtb = Khb + MD;
  unsigned short* AOb = Vtb + MD;

  cvt4_kernel<<<dim3((int)(DD/4/256), 4), 256, 0, stream>>>(Wq, Wk, Wv, Wo, Wqb, Wkb, Wvb, Wob, (int)(DD/4));

  gemm_qkv<<<dim3(512, 3), 256, 0, stream>>>(q, k, v, Wqb, Wkb, Wvb,
                                             bq, bk, bv, Qhb, Khb, Vtb);

  attn_kernel<<<dim3(64, 16), 256, 0, stream>>>(Qhb, Khb, Vtb, AOb);

  gemm_out<<<512, 256, 0, stream>>>(AOb, Wob, bo, (float*)d_out);
}

// Round 19
// 175.812 us; speedup vs baseline: 1.6984x; 1.6984x over previous
//
#include <hip/hip_runtime.h>
#include <hip/hip_bf16.h>

// B=4, S=2048, D=1024, H=16, DH=64. MHA forward, causal, f32 io.
// fused QKV proj GEMM reads f32 q/k/v directly: A staged as f32 via
// global_load_lds (swizzled), converted to bf16 on the LDS->reg fragment read
// (Q pre-scaled 0.125*log2e; V written transposed [b,h,dh,s]) -> flash attn
// (32x32 MFMA, swapped QK^T, in-register P, no-max exp2 softmax) -> out GEMM.
// Only weights go through a cvt kernel (4 MB). GEMMs at 3 blocks/CU.
// [R19 = restoration of the best-measured R13 configuration, 175.4 us]

#define B_ 4
#define S_ 2048
#define D_ 1024
#define H_ 16
#define DH_ 64
#define M_ (B_*S_)
#define MASKADD (-14427.0f)    // -10000 * log2(e)
#define QSCALE  (0.180336880f) // 0.125 * log2(e)

typedef __attribute__((ext_vector_type(8)))  __bf16 bf16x8;
typedef __attribute__((ext_vector_type(8)))  unsigned short ushort8;
typedef __attribute__((ext_vector_type(4)))  float f32x4;
typedef __attribute__((ext_vector_type(16))) float f32x16;

__device__ __forceinline__ unsigned short f2bf(float f) {
  __hip_bfloat16 h = __float2bfloat16(f);
  union { __hip_bfloat16 h; unsigned short u; } c; c.h = h; return c.u;
}

__device__ __forceinline__ f32x4 mfma16(bf16x8 a, bf16x8 b, f32x4 c) {
  return __builtin_amdgcn_mfma_f32_16x16x32_bf16(a, b, c, 0, 0, 0);
}
__device__ __forceinline__ f32x16 mfma32(bf16x8 a, bf16x8 b, f32x16 c) {
  return __builtin_amdgcn_mfma_f32_32x32x16_bf16(a, b, c, 0, 0, 0);
}

__device__ __forceinline__ unsigned cvtpk(float lo, float hi) {
  unsigned r;
  asm("v_cvt_pk_bf16_f32 %0, %1, %2" : "=v"(r) : "v"(lo), "v"(hi));
  return r;
}

__device__ __forceinline__ void gld_lds16(const void* g, void* l) {
  __builtin_amdgcn_global_load_lds(
      (const __attribute__((address_space(1))) unsigned int*)g,
      (__attribute__((address_space(3))) unsigned int*)l, 16, 0, 0);
}

// ---------------- f32 -> bf16 conversion (weights only) ----------------
__global__ void cvt4_kernel(const float* __restrict__ p0, const float* __restrict__ p1,
                            const float* __restrict__ p2, const float* __restrict__ p3,
                            unsigned short* __restrict__ o0, unsigned short* __restrict__ o1,
                            unsigned short* __restrict__ o2, unsigned short* __restrict__ o3,
                            int n4) {
  int i = blockIdx.x * blockDim.x + threadIdx.x;
  if (i >= n4) return;
  const float* in  = (blockIdx.y == 0) ? p0 : (blockIdx.y == 1 ? p1 : (blockIdx.y == 2 ? p2 : p3));
  unsigned short* out = (blockIdx.y == 0) ? o0 : (blockIdx.y == 1 ? o1 : (blockIdx.y == 2 ? o2 : o3));
  float4 f = reinterpret_cast<const float4*>(in)[i];
  ushort4 o;
  o.x = f2bf(f.x); o.y = f2bf(f.y); o.z = f2bf(f.z); o.w = f2bf(f.w);
  reinterpret_cast<ushort4*>(out)[i] = o;
}

// ---------------- GEMM body: C[M,N] = A[M,K] * W[N,K]^T + bias ------------
// F32A: A is f32, staged f32 into LDS via global_load_lds with XOR-(row&7)
// 16B-granule swizzle (pre-swizzled source), converted to bf16 by cvt_pk on
// the fragment read. Else A is bf16 via global_load_lds (linear).
// B (weights, bf16) always via global_load_lds.
// mode 0: bf16 head-permuted [B,H,S,DH]. mode 1: f32 row-major.
// mode 2: bf16 transposed per-head [B,H,DH,S]. sc: multiply by QSCALE.
template<bool F32A>
__device__ __forceinline__
void gemm_body(const void* __restrict__ Ap, const unsigned short* __restrict__ W,
               const float* __restrict__ bias, void* __restrict__ outp,
               int mode, bool sc,
               unsigned short* sA16, float* sA32, unsigned short* sB)
{
  const int tid  = threadIdx.x;
  const int lane = tid & 63, wid = tid >> 6;
  const int bx = blockIdx.x;
  const int j8 = bx & 7, i8 = bx >> 3;
  const int mt = j8*8 + (i8 >> 3), nt = i8 & 7;   // bijective: 64 x 8
  const int m0 = mt*128, n0 = nt*128;
  const int wr = wid >> 1, wc = wid & 1;
  const int g = lane >> 4;

  const float* A32 = (const float*)Ap;
  const unsigned short* A16 = (const unsigned short*)Ap;

  f32x4 acc[4][4];
  #pragma unroll
  for (int i = 0; i < 4; ++i)
    #pragma unroll
    for (int j = 0; j < 4; ++j)
      #pragma unroll
      for (int r = 0; r < 4; ++r) acc[i][j][r] = 0.0f;

  auto stageB = [&](int bufi, int kt) {
    const unsigned short* Wb = W + (size_t)n0*D_ + kt*32;
    #pragma unroll
    for (int p = 0; p < 2; ++p) {
      int r = 32*wid + 16*p + (lane >> 2);
      int c = (lane & 3) * 8;
      gld_lds16(Wb + (size_t)r*D_ + c, &sB[bufi*4096 + (32*wid + 16*p)*32]);
    }
  };
  auto stageA16 = [&](int bufi, int kt) {
    const unsigned short* Ab = A16 + (size_t)m0*D_ + kt*32;
    #pragma unroll
    for (int p = 0; p < 2; ++p) {
      int r = 32*wid + 16*p + (lane >> 2);
      int c = (lane & 3) * 8;
      gld_lds16(Ab + (size_t)r*D_ + c, &sA16[bufi*4096 + (32*wid + 16*p)*32]);
    }
  };
  // f32 A: 16 chunks of 8 rows (128 B/row); lane covers row ch*8+(lane>>3),
  // 16B granule (lane&7), source granule pre-swizzled by ((row&7)<<4).
  auto stageA32 = [&](int bufi, int kt) {
    const float* Ab = A32 + (size_t)m0*D_ + kt*32;
    #pragma unroll
    for (int p = 0; p < 4; ++p) {
      int ch = 4*wid + p;
      int row = ch*8 + (lane >> 3);
      int cbs = ((lane & 7) * 16) ^ ((lane >> 3) << 4);   // row&7 == lane>>3
      gld_lds16(Ab + (size_t)row*D_ + (cbs >> 2), &sA32[bufi*4096 + ch*256]);
    }
  };

  if (F32A) stageA32(0, 0); else stageA16(0, 0);
  stageB(0, 0);

  const int NK = D_/32;
  int buf = 0;
  for (int kt = 0; kt < NK; ++kt) {
    __syncthreads();                       // tile kt ready in buf
    if (kt + 1 < NK) {
      if (F32A) stageA32(buf ^ 1, kt + 1);
      else      stageA16(buf ^ 1, kt + 1);
      stageB(buf ^ 1, kt + 1);
    }

    bf16x8 aF[4], bF[4];
    #pragma unroll
    for (int i = 0; i < 4; ++i) {
      int row = 64*wr + 16*i + (lane & 15);
      if (F32A) {
        const char* base = (const char*)(sA32 + buf*4096) + row*128;
        int sw = (row & 7) << 4;
        f32x4 a0 = *(const f32x4*)(base + ((g*32)      ^ sw));
        f32x4 a1 = *(const f32x4*)(base + ((g*32 + 16) ^ sw));
        union { unsigned u[4]; bf16x8 v; } af;
        af.u[0] = cvtpk(a0[0], a0[1]);
        af.u[1] = cvtpk(a0[2], a0[3]);
        af.u[2] = cvtpk(a1[0], a1[1]);
        af.u[3] = cvtpk(a1[2], a1[3]);
        aF[i] = af.v;
      } else {
        aF[i] = *(const bf16x8*)&sA16[buf*4096 + row*32 + g*8];
      }
    }
    #pragma unroll
    for (int j = 0; j < 4; ++j)
      bF[j] = *(const bf16x8*)&sB[buf*4096 + (64*wc + 16*j + (lane & 15))*32 + g*8];

    #pragma unroll
    for (int i = 0; i < 4; ++i)
      #pragma unroll
      for (int j = 0; j < 4; ++j)
        acc[i][j] = mfma16(aF[i], bF[j], acc[i][j]);
    buf ^= 1;
  }

  #pragma unroll
  for (int i = 0; i < 4; ++i) {
    int gr0 = m0 + 64*wr + 16*i + ((lane >> 4) << 2);
    #pragma unroll
    for (int j = 0; j < 4; ++j) {
      int gc = n0 + 64*wc + 16*j + (lane & 15);
      float bv = bias[gc];
      if (mode == 2) {
        int b = gr0 >> 11, s = gr0 & (S_ - 1);
        int hh = gc >> 6, dh = gc & (DH_ - 1);
        ushort4 o;
        o.x = f2bf(acc[i][j][0] + bv); o.y = f2bf(acc[i][j][1] + bv);
        o.z = f2bf(acc[i][j][2] + bv); o.w = f2bf(acc[i][j][3] + bv);
        *(ushort4*)&((unsigned short*)outp)[(((size_t)b*H_ + hh)*DH_ + dh)*S_ + s] = o;
      } else {
        #pragma unroll
        for (int r = 0; r < 4; ++r) {
          float v = acc[i][j][r] + bv;
          if (sc) v *= QSCALE;
          int gr = gr0 + r;
          if (mode == 0) {
            int b = gr >> 11, s = gr & (S_ - 1);
            int hh = gc >> 6, dh = gc & (DH_ - 1);
            ((unsigned short*)outp)[(((size_t)b*H_ + hh)*S_ + s)*DH_ + dh] = f2bf(v);
          } else {
            ((float*)outp)[(size_t)gr*D_ + gc] = v;
          }
        }
      }
    }
  }
}

// fused Q/K/V projections from f32 inputs: grid (512, 3); y selects tensor
__global__ __launch_bounds__(256, 3)
void gemm_qkv(const float* __restrict__ Aq, const float* __restrict__ Ak,
              const float* __restrict__ Av,
              const unsigned short* __restrict__ Wq_, const unsigned short* __restrict__ Wk_,
              const unsigned short* __restrict__ Wv_,
              const float* __restrict__ bq_, const float* __restrict__ bk_,
              const float* __restrict__ bv_,
              unsigned short* __restrict__ Oq, unsigned short* __restrict__ Ok,
              unsigned short* __restrict__ Ov)
{
  __shared__ float          sA32[2*4096];   // 32 KB
  __shared__ unsigned short sB  [2*4096];   // 16 KB
  const int y = blockIdx.y;
  const float* A = (y == 0) ? Aq : (y == 1 ? Ak : Av);
  const unsigned short* W = (y == 0) ? Wq_ : (y == 1 ? Wk_ : Wv_);
  const float* bias        = (y == 0) ? bq_ : (y == 1 ? bk_ : bv_);
  unsigned short* outp     = (y == 0) ? Oq  : (y == 1 ? Ok  : Ov);
  gemm_body<true>(A, W, bias, outp, (y == 2) ? 2 : 0, y == 0, nullptr, sA32, sB);
}

__global__ __launch_bounds__(256, 3)
void gemm_out(const unsigned short* __restrict__ A, const unsigned short* __restrict__ W,
              const float* __restrict__ bias, float* __restrict__ outp)
{
  __shared__ unsigned short sA16[2*4096];   // 16 KB
  __shared__ unsigned short sB  [2*4096];   // 16 KB
  gemm_body<false>(A, W, bias, outp, 1, false, sA16, nullptr, sB);
}

// ---------------- Flash attention (32x32 MFMA, in-register P) --------------
// grid (64 bh, 16): bx = bh (XCD-local K/V), by -> chunk = 15-by (longest
// first). Block = 4 waves x 32 q-rows = 128 q. Wave w: q = chunk*128 + w*32
// + (lane&31). KVBLK=64 staged tile (two 32-kv subtiles), double-buffered,
// XOR-swizzled rows, 1 barrier/tile.
// QK^T swapped at 32x32: S^T lane layout q=lane&31, kv=(r&3)+8(r>>2)+4(l>>5).
// Operand k-layout (stacked K8 blocks): C-regs st[8hh+j] ARE the PV B-operand
// fragment for kv-chunk hh -- pack with 4 cvt_pk, no cross-lane ops.
// vf loads match: two b64 reads at X and X+16, X = 64*sub+32*hh+8*h5.
__global__ __launch_bounds__(256)
void attn_kernel(const unsigned short* __restrict__ Qh, const unsigned short* __restrict__ Kh,
                 const unsigned short* __restrict__ Vt, unsigned short* __restrict__ AO)
{
  __shared__ unsigned short sK [2][64*64];
  __shared__ unsigned short sVt[2][64*64];

  const int tid = threadIdx.x, lane = tid & 63, wid = tid >> 6;
  const int l31 = lane & 31, h5 = lane >> 5;
  const int bh = blockIdx.x;
  const int chunk = 15 - (int)blockIdx.y;
  const int bb = bh >> 4, hd = bh & 15;
  const unsigned short* Qb = Qh + (size_t)bh * S_ * DH_;
  const unsigned short* Kb = Kh + (size_t)bh * S_ * DH_;
  const unsigned short* Vb = Vt + (size_t)bh * DH_ * S_;
  const int qc0 = chunk * 128;
  const int NT  = 2*chunk + 2;
  const int qw0 = qc0 + wid*32;            // wave's first q row
  const int q   = qw0 + l31;               // this lane's q row

  bf16x8 qF[4];
  #pragma unroll
  for (int c = 0; c < 4; ++c)
    qF[c] = *(const bf16x8*)(Qb + (size_t)q*DH_ + c*16 + h5*8);

  f32x16 zz;
  #pragma unroll
  for (int r = 0; r < 16; ++r) zz[r] = 0.0f;
  f32x16 accO0 = zz, accO1 = zz;           // d-halves 0..31, 32..63
  float lsum = 0.0f;

  auto stageK = [&](int bufi, int t) {
    #pragma unroll
    for (int p = 0; p < 2; ++p) {
      int ch = 2*wid + p;
      int row = ch*8 + (lane >> 3);
      int cbs = ((lane & 7) * 16) ^ ((row & 7) << 4);
      gld_lds16(Kb + (size_t)(t*64 + row)*DH_ + (cbs >> 1), &sK[bufi][ch*512]);
    }
  };
  auto stageV = [&](int bufi, int t) {
    #pragma unroll
    for (int p = 0; p < 2; ++p) {
      int ch = 2*wid + p;
      int row = ch*8 + (lane >> 3);          // row = dh
      int cbs = ((lane & 7) * 16) ^ ((row & 7) << 4);
      gld_lds16(Vb + (size_t)row*S_ + t*64 + (cbs >> 1), &sVt[bufi][ch*512]);
    }
  };

  stageK(0, 0);
  stageV(0, 0);

  int buf = 0;
  for (int t = 0; t < NT; ++t) {
    __syncthreads();        // tile t staged; prev-buf reads complete
    if (t + 1 < NT) { stageK(buf ^ 1, t + 1); stageV(buf ^ 1, t + 1); }

    #pragma unroll
    for (int sub = 0; sub < 2; ++sub) {
      const int kv0 = t*64 + sub*32;
      if (kv0 > qw0 + 31) continue;          // subtile fully masked (uniform)
      const bool dodiag = (kv0 + 31 > qw0);

      // ---- QK^T: S^T = K Q^T, chained over 4 d-chunks ----
      f32x16 st = zz;
      __builtin_amdgcn_s_setprio(1);
      #pragma unroll
      for (int c = 0; c < 4; ++c) {
        int row = sub*32 + l31;              // kv row in tile
        const char* base = (const char*)&sK[buf][0] + row*128;
        bf16x8 kf = *(const bf16x8*)(base + ((32*c + 16*h5) ^ ((row & 7) << 4)));
        st = mfma32(kf, qF[c], st);
      }
      __builtin_amdgcn_s_setprio(0);

      // ---- mask + exp2 + row-sum ----
      #pragma unroll
      for (int r = 0; r < 16; ++r) {
        float x = st[r];
        if (dodiag) {
          int kv = kv0 + (r & 3) + 8*(r >> 2) + 4*h5;
          if (kv > q) x += MASKADD;
        }
        x = __builtin_amdgcn_exp2f(x);
        st[r] = x;
        lsum += x;
      }

      // ---- per 16-kv chunk: pack P (C-regs are the B fragment), PV ----
      #pragma unroll
      for (int hh = 0; hh < 2; ++hh) {
        union { unsigned u[4]; bf16x8 v; } pb;
        pb.u[0] = cvtpk(st[8*hh+0], st[8*hh+1]);
        pb.u[1] = cvtpk(st[8*hh+2], st[8*hh+3]);
        pb.u[2] = cvtpk(st[8*hh+4], st[8*hh+5]);
        pb.u[3] = cvtpk(st[8*hh+6], st[8*hh+7]);

        __builtin_amdgcn_s_setprio(1);
        #pragma unroll
        for (int dh = 0; dh < 2; ++dh) {
          int row = dh*32 + l31;             // d row
          const char* base = (const char*)&sVt[buf][0] + row*128;
          int sw = (row & 7) << 4;
          int X = 64*sub + 32*hh + 8*h5;
          union { uint2 g[2]; bf16x8 v; } vv;
          vv.g[0] = *(const uint2*)(base + ((X)      ^ sw));
          vv.g[1] = *(const uint2*)(base + ((X + 16) ^ sw));
          if (dh == 0) accO0 = mfma32(vv.v, pb.v, accO0);
          else         accO1 = mfma32(vv.v, pb.v, accO1);
        }
        __builtin_amdgcn_s_setprio(0);
      }
    }
    buf ^= 1;
  }

  // ---- epilogue: combine the two kv-half sums, scale, store ----
  float lt = lsum + __shfl_xor(lsum, 32, 64);
  float inv = 1.0f / lt;
  unsigned short* ao = AO + ((size_t)bb*S_ + q)*D_ + hd*DH_;
  #pragma unroll
  for (int dh = 0; dh < 2; ++dh) {
    const f32x16 A = dh ? accO1 : accO0;
    #pragma unroll
    for (int rq = 0; rq < 4; ++rq) {
      ushort4 o;
      o.x = f2bf(A[4*rq+0] * inv);
      o.y = f2bf(A[4*rq+1] * inv);
      o.z = f2bf(A[4*rq+2] * inv);
      o.w = f2bf(A[4*rq+3] * inv);
      int dbase = dh*32 + 8*rq + 4*h5;       // d = dbase + (r&3)
      *(ushort4*)&ao[dbase] = o;
    }
  }
}

// ---------------- launch ----------------
extern "C" void kernel_launch(void* const* d_in, const int* in_sizes, int n_in,
                              void* d_out, int out_size, void* d_ws, size_t ws_size,
                              hipStream_t stream)
{
  const float* q  = (const float*)d_in[0];
  const float* k  = (const float*)d_in[1];
  const float* v  = (const float*)d_in[2];
  const float* Wq = (const float*)d_in[4];
  const float* bq = (const float*)d_in[5];
  const float* Wk = (const float*)d_in[6];
  const float* bk = (const float*)d_in[7];
  const float* Wv = (const float*)d_in[8];
  const float* bv = (const float*)d_in[9];
  const float* Wo = (const float*)d_in[10];
  const float* bo = (const float*)d_in[11];

  unsigned short* ws = (unsigned short*)d_ws;
  const size_t MD = (size_t)M_ * D_;
  const size_t DD = (size_t)D_ * D_;
  unsigned short* Wqb = ws;
  unsigned short* Wkb = Wqb + DD;
  unsigned short* Wvb = Wkb + DD;
  unsigned short* Wob = Wvb + DD;
  unsigned short* Qhb = Wob + DD;
  unsigned short* Khb = Qhb + MD;
  unsigned short* Vtb = Khb + MD;
  unsigned short* AOb = Vtb + MD;

  cvt4_kernel<<<dim3((int)(DD/4/256), 4), 256, 0, stream>>>(Wq, Wk, Wv, Wo, Wqb, Wkb, Wvb, Wob, (int)(DD/4));

  gemm_qkv<<<dim3(512, 3), 256, 0, stream>>>(q, k, v, Wqb, Wkb, Wvb,
                                             bq, bk, bv, Qhb, Khb, Vtb);

  attn_kernel<<<dim3(64, 16), 256, 0, stream>>>(Qhb, Khb, Vtb, AOb);

  gemm_out<<<512, 256, 0, stream>>>(AOb, Wob, bo, (float*)d_out);
}